// Round 4
// baseline (124.524 us; speedup 1.0000x reference)
//
#include <hip/hip_runtime.h>

// logits = relu(T1[q] + sum_s T2[t_s]) @ W2^T + b2, vocab=64 so layer-1 is
// 9 table-row gathers from LDS-resident fp16 tables.
//
// R3 changes:
//  - MFMA operand swap: compute D = W2frag * xfrag (was x * W2). A and B
//    fragments of mfma_f32_16x16x32_f16 share the same lane layout, so the
//    swap transposes D: lane now holds 4 CONSECUTIVE logits (m = qd*4+r of
//    tile nt) of ONE element (n = l15) -> acc[nt] stores directly as
//    dwordx4 (epilogue transpose movs eliminated, 16/iter), bias init is a
//    f32x4 load of b2[nt*16+qd*4..].
//  - prep also emits W2 in fragment-ready fp16 layout (8 KB after the
//    tables in ws): lru prologue = 8 b128 loads, no f32->f16 pack ops.
//  - keeps R2 geometry (1024 blocks x 4 iters, dedup token loads + shfl
//    broadcast) and R1 fp16 packed gather-accumulate.

#define RSTRIDE_W 36                    // dwords per LDS row (32 data + 4 pad)
#define T2_OFF_W  (64 * RSTRIDE_W)      // 2304
#define LDS_DW    (2 * 64 * RSTRIDE_W)  // 4608 dwords = 18432 B
#define W2F_OFF_H (128 * 2 * RSTRIDE_W) // 9216 halves = 18432 B into ws

typedef __attribute__((ext_vector_type(4))) float    f32x4;
typedef __attribute__((ext_vector_type(4))) int      i32x4;
typedef __attribute__((ext_vector_type(8))) _Float16 f16x8;

// grid 136 x 64:
//  blocks 0..127: T1 (query half, b1 folded) / T2 (memory half, 1/8 folded)
//  blocks 128..135: W2 -> fragment-ready fp16 (block = (nt,ks), lane = lane)
__global__ void prep_kernel(const float* __restrict__ embed,
                            const float* __restrict__ W1,
                            const float* __restrict__ b1,
                            const float* __restrict__ W2,
                            unsigned short* __restrict__ T) {
  const int bid = blockIdx.x;
  const int j   = threadIdx.x;
  if (bid < 128) {
    const int t    = bid & 63;
    const int half = bid >> 6;
    const f32x4* w4 = (const f32x4*)(W1 + j * 128 + half * 64);
    const f32x4* e4 = (const f32x4*)(embed + t * 64);
    float acc = 0.f;
#pragma unroll
    for (int k = 0; k < 16; ++k) {
      f32x4 a = w4[k], b = e4[k];
      acc += a[0] * b[0] + a[1] * b[1] + a[2] * b[2] + a[3] * b[3];
    }
    const float outv = half ? acc * 0.125f : acc + b1[j];
    ((_Float16*)T)[half * (64 * 2 * RSTRIDE_W) + t * (2 * RSTRIDE_W) + j] =
        (_Float16)outv;
  } else {
    const int b   = bid - 128;      // 0..7 = (nt<<1)|ks
    const int nt  = b >> 1;
    const int ks  = b & 1;
    const int l15 = j & 15;
    const int qd  = j >> 4;
    // lane provides A[row = l15 -> logit nt*16+l15][k = ks*32 + qd*8 + i]
    const float* wr = W2 + (nt * 16 + l15) * 64 + ks * 32 + qd * 8;
    f32x4 w0 = *(const f32x4*)(wr);
    f32x4 w1 = *(const f32x4*)(wr + 4);
    f16x8 f;
    f[0] = (_Float16)w0[0]; f[1] = (_Float16)w0[1];
    f[2] = (_Float16)w0[2]; f[3] = (_Float16)w0[3];
    f[4] = (_Float16)w1[0]; f[5] = (_Float16)w1[1];
    f[6] = (_Float16)w1[2]; f[7] = (_Float16)w1[3];
    *(f16x8*)((_Float16*)T + W2F_OFF_H + (size_t)(b * 64 + j) * 8) = f;
  }
}

// 1024 blocks x 256 threads; each wave: 4 iters x 16 elements (one MFMA
// tile row each). Lane (qd=lane>>4, l15=lane&15) gathers features
// qd*8..+7 (ks0) and 32+qd*8..+7 (ks1) of element b0+l15's 9 table rows
// as packed fp16, accumulates with v_pk_add_f16, ReLUs, then per n-tile
// mfma(W2frag, xfrag) -> lane's acc = 4 consecutive logits of element
// b0+l15 -> direct dwordx4 store.
__global__ __launch_bounds__(256, 4) void lru_kernel(
    const int*      __restrict__ seqs,
    const int*      __restrict__ qtok,
    const float*    __restrict__ b2,
    const unsigned* __restrict__ T,
    float*          __restrict__ out) {
  __shared__ __align__(16) unsigned lds[LDS_DW];
  const int tid = threadIdx.x;

  {  // stage tables (1152 uint4 = 4*256 + 128)
    const uint4* src = (const uint4*)T;
    uint4*       dst = (uint4*)lds;
#pragma unroll
    for (int r = 0; r < 4; ++r) dst[tid + r * 256] = src[tid + r * 256];
    if (tid < 128) dst[tid + 1024] = src[tid + 1024];
  }

  const int lane = tid & 63;
  const int wv   = tid >> 6;
  const int qd   = lane >> 4;
  const int l15  = lane & 15;

  // fragment-ready W2 (A-operand) + per-lane bias vector
  f16x8 afW[4][2];
  f32x4 bb4[4];
  {
    const _Float16* w2f = (const _Float16*)T + W2F_OFF_H;
#pragma unroll
    for (int nt = 0; nt < 4; ++nt) {
#pragma unroll
      for (int ks = 0; ks < 2; ++ks)
        afW[nt][ks] =
            *(const f16x8*)(w2f + (size_t)(((nt << 1) | ks) * 64 + lane) * 8);
      bb4[nt] = *(const f32x4*)(b2 + nt * 16 + qd * 4);
    }
  }

  // each lane loads its OWN element's tokens once (covers all 4 iters)
  const int wbase  = blockIdx.x * 256 + wv * 64;
  const int myelem = wbase + lane;
  const int* srow  = seqs + myelem * 24;
  const i32x4 t0 = __builtin_nontemporal_load((const i32x4*)(srow + 12));
  const i32x4 t1 = __builtin_nontemporal_load((const i32x4*)(srow + 16));
  const i32x4 t2 = __builtin_nontemporal_load((const i32x4*)(srow + 20));
  const int   tq = __builtin_nontemporal_load(qtok + myelem);
  __syncthreads();

#pragma unroll
  for (int it = 0; it < 4; ++it) {
    const int b0  = wbase + it * 16;
    const int src = it * 16 + l15;   // lane holding this element's tokens

    const int qt = __shfl(tq, src);
    int tk[8];
    tk[0] = __shfl(t0.w, src);
    tk[1] = __shfl(t1.x, src);
    tk[2] = __shfl(t1.y, src);
    tk[3] = __shfl(t1.z, src);
    tk[4] = __shfl(t1.w, src);
    tk[5] = __shfl(t2.x, src);
    tk[6] = __shfl(t2.y, src);
    tk[7] = __shfl(t2.z, src);

    // packed fp16 accumulators: a0 = features qd*8..+7, a1 = 32+qd*8..+7
    f16x8 a0, a1;
    {
      const f16x8* r1 = (const f16x8*)(lds + qt * RSTRIDE_W + qd * 4);
      a0 = r1[0];          // dwords [qd*4 .. qd*4+3]
      a1 = r1[4];          // +16 dwords (ks1 half)
    }
#pragma unroll
    for (int s = 0; s < 8; ++s) {
      const f16x8* r2 =
          (const f16x8*)(lds + T2_OFF_W + tk[s] * RSTRIDE_W + qd * 4);
      a0 += r2[0];
      a1 += r2[4];
    }
    const f16x8 z = {(_Float16)0, (_Float16)0, (_Float16)0, (_Float16)0,
                     (_Float16)0, (_Float16)0, (_Float16)0, (_Float16)0};
    const f16x8 afA = __builtin_elementwise_max(a0, z);
    const f16x8 afB = __builtin_elementwise_max(a1, z);

    // operand-swapped MFMA: lane = element b0+l15, regs = logits
    // nt*16 + qd*4 + r -> direct coalesced dwordx4 stores, no transpose
    float* op = out + (size_t)(b0 + l15) * 64 + qd * 4;
#pragma unroll
    for (int nt = 0; nt < 4; ++nt) {
      f32x4 a = bb4[nt];
      a = __builtin_amdgcn_mfma_f32_16x16x32_f16(afW[nt][0], afA, a, 0, 0, 0);
      a = __builtin_amdgcn_mfma_f32_16x16x32_f16(afW[nt][1], afB, a, 0, 0, 0);
      __builtin_nontemporal_store(a, (f32x4*)(op + nt * 16));
    }
  }
}

extern "C" void kernel_launch(void* const* d_in, const int* in_sizes, int n_in,
                              void* d_out, int out_size, void* d_ws, size_t ws_size,
                              hipStream_t stream) {
  const int*   seqs  = (const int*)d_in[0];
  const int*   qtokp = (const int*)d_in[1];
  const float* embed = (const float*)d_in[2];
  const float* W1    = (const float*)d_in[3];
  const float* b1    = (const float*)d_in[4];
  const float* W2    = (const float*)d_in[5];
  const float* b2    = (const float*)d_in[6];
  float*       outp  = (float*)d_out;

  prep_kernel<<<dim3(136), dim3(64), 0, stream>>>(embed, W1, b1, W2,
                                                  (unsigned short*)d_ws);
  lru_kernel<<<dim3(1024), dim3(256), 0, stream>>>(seqs, qtokp, b2,
                                                   (const unsigned*)d_ws, outp);
}

// Round 5
// 117.356 us; speedup vs baseline: 1.0611x; 1.0611x over previous
//
#include <hip/hip_runtime.h>

// logits = relu(T1[q] + sum_s T2[t_s]) @ W2^T + b2, vocab=64 so layer-1 is
// 9 table-row gathers from LDS-resident fp16 tables.
//
// R4 = R2 base + R3's operand swap, minimal diff:
//  - MFMA computes D = W2frag * xfrag; A/B fragments of
//    mfma_f32_16x16x32_f16 share the lane layout, so lane (qd,l15) gets
//    acc[r] = logit nt*16+qd*4+r of element b0+l15 -> direct coalesced
//    dwordx4 stores, no epilogue transpose movs.
//  - W2 loaded fp32 straight from global in the lru prologue (R3's
//    fragment-ready ws stage reverted - it added a ws round-trip for no
//    measured gain).
//  - packed-token shfl: lane packs its 8 memory tokens into 2 dwords
//    once; per iteration the broadcast is 3 shfls (pk0,pk1,qt) not 9,
//    and all 4 iterations' tokens live in 3 VGPRs.
//  - keeps R2 geometry (1024 blocks x 4 iters, dedup per-lane token
//    loads) and R1 fp16 packed gather-accumulate (v_pk_add_f16 on LDS
//    dwords, v_pk_max_f16 ReLU).

#define RSTRIDE_W 36                    // dwords per LDS row (32 data + 4 pad)
#define T2_OFF_W  (64 * RSTRIDE_W)      // 2304
#define LDS_DW    (2 * 64 * RSTRIDE_W)  // 4608 dwords = 18432 B

typedef __attribute__((ext_vector_type(4))) float    f32x4;
typedef __attribute__((ext_vector_type(4))) int      i32x4;
typedef __attribute__((ext_vector_type(8))) _Float16 f16x8;

// 32 blocks x 256 threads; job = (half, token) = blockIdx*4 + (tid>>6),
// thread j = output feature. T1 folds b1; T2 folds the 1/8 mean.
__global__ void prep_kernel(const float* __restrict__ embed,
                            const float* __restrict__ W1,
                            const float* __restrict__ b1,
                            unsigned short* __restrict__ T) {
  const int job  = blockIdx.x * 4 + (threadIdx.x >> 6);
  const int j    = threadIdx.x & 63;
  const int t    = job & 63;
  const int half = job >> 6;
  const f32x4* w4 = (const f32x4*)(W1 + j * 128 + half * 64);
  const f32x4* e4 = (const f32x4*)(embed + t * 64);
  float acc = 0.f;
#pragma unroll
  for (int k = 0; k < 16; ++k) {
    f32x4 a = w4[k], b = e4[k];
    acc += a[0] * b[0] + a[1] * b[1] + a[2] * b[2] + a[3] * b[3];
  }
  const float outv = half ? acc * 0.125f : acc + b1[j];
  ((_Float16*)T)[half * (64 * 2 * RSTRIDE_W) + t * (2 * RSTRIDE_W) + j] =
      (_Float16)outv;
}

// 1024 blocks x 256 threads; each wave: 4 iters x 16 elements (one MFMA
// tile each). Lane (qd=lane>>4, l15=lane&15) gathers features qd*8..+7
// (ks0) and 32+qd*8..+7 (ks1) of element b0+l15's 9 table rows as packed
// fp16, accumulates with v_pk_add_f16, ReLUs, then per n-tile
// mfma(W2frag, xfrag) -> lane's acc = 4 consecutive logits -> direct
// dwordx4 store.
__global__ __launch_bounds__(256, 4) void lru_kernel(
    const int*      __restrict__ seqs,
    const int*      __restrict__ qtok,
    const float*    __restrict__ W2,
    const float*    __restrict__ b2,
    const unsigned* __restrict__ T,
    float*          __restrict__ out) {
  __shared__ __align__(16) unsigned lds[LDS_DW];
  const int tid = threadIdx.x;

  {  // stage tables (1152 uint4 = 4*256 + 128)
    const uint4* src = (const uint4*)T;
    uint4*       dst = (uint4*)lds;
#pragma unroll
    for (int r = 0; r < 4; ++r) dst[tid + r * 256] = src[tid + r * 256];
    if (tid < 128) dst[tid + 1024] = src[tid + 1024];
  }

  const int lane = tid & 63;
  const int wv   = tid >> 6;
  const int qd   = lane >> 4;
  const int l15  = lane & 15;

  // A-operand fragments from W2 (fp32 global -> fp16):
  // lane supplies A[m = l15 -> logit nt*16+l15][k = ks*32 + qd*8 + i]
  f16x8 afW[4][2];
  f32x4 bb4[4];
#pragma unroll
  for (int nt = 0; nt < 4; ++nt) {
    const float* wr = W2 + (nt * 16 + l15) * 64 + qd * 8;
#pragma unroll
    for (int ks = 0; ks < 2; ++ks) {
      f32x4 w0 = *(const f32x4*)(wr + ks * 32);
      f32x4 w1 = *(const f32x4*)(wr + ks * 32 + 4);
      f16x8 f;
      f[0] = (_Float16)w0[0]; f[1] = (_Float16)w0[1];
      f[2] = (_Float16)w0[2]; f[3] = (_Float16)w0[3];
      f[4] = (_Float16)w1[0]; f[5] = (_Float16)w1[1];
      f[6] = (_Float16)w1[2]; f[7] = (_Float16)w1[3];
      afW[nt][ks] = f;
    }
    bb4[nt] = *(const f32x4*)(b2 + nt * 16 + qd * 4);
  }

  // each lane loads its OWN element's tokens once (covers all 4 iters),
  // packs the 8 memory tokens into 2 dwords (byte fields, values < 64)
  const int wbase  = blockIdx.x * 256 + wv * 64;
  const int myelem = wbase + lane;
  const int* srow  = seqs + myelem * 24;
  const i32x4 t0 = __builtin_nontemporal_load((const i32x4*)(srow + 12));
  const i32x4 t1 = __builtin_nontemporal_load((const i32x4*)(srow + 16));
  const i32x4 t2 = __builtin_nontemporal_load((const i32x4*)(srow + 20));
  const int   tq = __builtin_nontemporal_load(qtok + myelem);
  const int pk0 = t0.w | (t1.x << 8) | (t1.y << 16) | (t1.z << 24);
  const int pk1 = t1.w | (t2.x << 8) | (t2.y << 16) | (t2.z << 24);
  __syncthreads();

#pragma unroll
  for (int it = 0; it < 4; ++it) {
    const int b0  = wbase + it * 16;
    const int src = it * 16 + l15;   // lane holding this element's tokens

    const int u0 = __shfl(pk0, src);
    const int u1 = __shfl(pk1, src);
    const int qt = __shfl(tq,  src);

    // packed fp16 accumulators: a0 = features qd*8..+7, a1 = 32+qd*8..+7
    f16x8 a0, a1;
    {
      const f16x8* r1 = (const f16x8*)(lds + qt * RSTRIDE_W + qd * 4);
      a0 = r1[0];          // dwords [qt*36+qd*4 .. +3]
      a1 = r1[4];          // +16 dwords (ks1 half)
    }
#pragma unroll
    for (int s = 0; s < 4; ++s) {
      const int tk = (u0 >> (8 * s)) & 63;
      const f16x8* r2 =
          (const f16x8*)(lds + T2_OFF_W + tk * RSTRIDE_W + qd * 4);
      a0 += r2[0];
      a1 += r2[4];
    }
#pragma unroll
    for (int s = 0; s < 4; ++s) {
      const int tk = (u1 >> (8 * s)) & 63;
      const f16x8* r2 =
          (const f16x8*)(lds + T2_OFF_W + tk * RSTRIDE_W + qd * 4);
      a0 += r2[0];
      a1 += r2[4];
    }
    const f16x8 z = {(_Float16)0, (_Float16)0, (_Float16)0, (_Float16)0,
                     (_Float16)0, (_Float16)0, (_Float16)0, (_Float16)0};
    const f16x8 afA = __builtin_elementwise_max(a0, z);
    const f16x8 afB = __builtin_elementwise_max(a1, z);

    // operand-swapped MFMA: lane = element b0+l15, regs = logits
    // nt*16 + qd*4 + r -> direct coalesced dwordx4 stores
    float* op = out + (size_t)(b0 + l15) * 64 + qd * 4;
#pragma unroll
    for (int nt = 0; nt < 4; ++nt) {
      f32x4 a = bb4[nt];
      a = __builtin_amdgcn_mfma_f32_16x16x32_f16(afW[nt][0], afA, a, 0, 0, 0);
      a = __builtin_amdgcn_mfma_f32_16x16x32_f16(afW[nt][1], afB, a, 0, 0, 0);
      __builtin_nontemporal_store(a, (f32x4*)(op + nt * 16));
    }
  }
}

extern "C" void kernel_launch(void* const* d_in, const int* in_sizes, int n_in,
                              void* d_out, int out_size, void* d_ws, size_t ws_size,
                              hipStream_t stream) {
  const int*   seqs  = (const int*)d_in[0];
  const int*   qtokp = (const int*)d_in[1];
  const float* embed = (const float*)d_in[2];
  const float* W1    = (const float*)d_in[3];
  const float* b1    = (const float*)d_in[4];
  const float* W2    = (const float*)d_in[5];
  const float* b2    = (const float*)d_in[6];
  float*       outp  = (float*)d_out;

  prep_kernel<<<dim3(32), dim3(256), 0, stream>>>(embed, W1, b1,
                                                  (unsigned short*)d_ws);
  lru_kernel<<<dim3(1024), dim3(256), 0, stream>>>(seqs, qtokp, W2, b2,
                                                   (const unsigned*)d_ws, outp);
}